// Round 5
// baseline (730.945 us; speedup 1.0000x reference)
//
#include <hip/hip_runtime.h>
#include <hip/hip_bf16.h>
#include <math.h>

#define N_GENE 50000
#define N_DIS  25000
#define F_GENE 512
#define F_DIS  256
#define E_EDGES 150000
#define BN_EPS 1e-5f

typedef unsigned short u16;
typedef short s16x8 __attribute__((ext_vector_type(8)));
typedef float f32x4 __attribute__((ext_vector_type(4)));

__device__ __forceinline__ u16 f2bf(float f) {
    union { float f; unsigned u; } c; c.f = f;
    unsigned u = c.u;
    unsigned rounding = 0x7FFFu + ((u >> 16) & 1u);
    return (u16)((u + rounding) >> 16);
}
__device__ __forceinline__ void load_bf16x8(const u16* p, float* f) {
    uint4 q = *reinterpret_cast<const uint4*>(p);
    unsigned w0 = q.x, w1 = q.y, w2 = q.z, w3 = q.w;
    f[0] = __uint_as_float(w0 << 16); f[1] = __uint_as_float(w0 & 0xffff0000u);
    f[2] = __uint_as_float(w1 << 16); f[3] = __uint_as_float(w1 & 0xffff0000u);
    f[4] = __uint_as_float(w2 << 16); f[5] = __uint_as_float(w2 & 0xffff0000u);
    f[6] = __uint_as_float(w3 << 16); f[7] = __uint_as_float(w3 & 0xffff0000u);
}

// ---------------- zero fill ----------------
__global__ void zero_kernel(int* p, int n) {
    int i = blockIdx.x * 256 + threadIdx.x;
    if (i < n) p[i] = 0;
}

// ---- W pre-transpose: wt[n*K+k] = bf16(W[k*N+n]) ----
__global__ void wtrans_kernel(const float* __restrict__ W, u16* __restrict__ wt, int K, int N) {
    int i = blockIdx.x * 256 + threadIdx.x;
    if (i >= K * N) return;
    int k = i / N, n = i - k * N;
    wt[n * K + k] = f2bf(W[i]);
}

// ---- MFMA GEMM v2: out[M,NFULL] tile = A[M,K] @ Wt[N,K]^T ----
// k-outer / n-inner: per k-chunk 1 A-frag + 8 B-frags + 8 MFMAs (8 indep acc chains).
// A is f32 or bf16 (A_BF16). Block = 4 waves x 16 rows; gridDim.y picks 128-col slab.
template <int K, int NFULL, bool A_BF16, bool RELU_BIAS, bool OUT_BF16>
__global__ __launch_bounds__(256) void mfma_gemm(const void* __restrict__ Ap,
                                                 const u16* __restrict__ Wt,
                                                 const float* __restrict__ bias,
                                                 void* __restrict__ outp, int M) {
    constexpr int KC = K / 32;
    int wave = threadIdx.x >> 6;
    int lane = threadIdx.x & 63;
    int m0 = (blockIdx.x * 4 + wave) * 16;
    if (m0 >= M) return;                 // wave-uniform
    int n0 = blockIdx.y * 128;
    int mrow = lane & 15;
    int quad = lane >> 4;
    int row = m0 + mrow;
    int arow = row < M ? row : M - 1;    // clamp OOB loads; stores guarded below

    const u16* bbase = Wt + (size_t)(n0 + mrow) * K + quad * 8;

    f32x4 acc[8];
#pragma unroll
    for (int t = 0; t < 8; t++) acc[t] = (f32x4){0.f, 0.f, 0.f, 0.f};

#pragma unroll 4
    for (int kc = 0; kc < KC; kc++) {
        s16x8 af;
        if (A_BF16) {
            af = *reinterpret_cast<const s16x8*>((const u16*)Ap + (size_t)arow * K + kc * 32 + quad * 8);
        } else {
            const float* ap = (const float*)Ap + (size_t)arow * K + kc * 32 + quad * 8;
            float4 lo = *reinterpret_cast<const float4*>(ap);
            float4 hi = *reinterpret_cast<const float4*>(ap + 4);
            af[0] = (short)f2bf(lo.x); af[1] = (short)f2bf(lo.y);
            af[2] = (short)f2bf(lo.z); af[3] = (short)f2bf(lo.w);
            af[4] = (short)f2bf(hi.x); af[5] = (short)f2bf(hi.y);
            af[6] = (short)f2bf(hi.z); af[7] = (short)f2bf(hi.w);
        }
#pragma unroll
        for (int t = 0; t < 8; t++) {
            s16x8 bfr = *reinterpret_cast<const s16x8*>(bbase + (size_t)t * 16 * K + kc * 32);
            acc[t] = __builtin_amdgcn_mfma_f32_16x16x32_bf16(af, bfr, acc[t], 0, 0, 0);
        }
    }

#pragma unroll
    for (int t = 0; t < 8; t++) {
        int col = n0 + t * 16 + mrow;
#pragma unroll
        for (int r = 0; r < 4; r++) {
            int orow = m0 + quad * 4 + r;
            if (orow < M) {
                float v = acc[t][r];
                if (RELU_BIAS) v = fmaxf(v + bias[col], 0.f);
                if (OUT_BF16)
                    ((u16*)outp)[(size_t)orow * NFULL + col] = f2bf(v);
                else
                    ((float*)outp)[(size_t)orow * NFULL + col] = v;
            }
        }
    }
}

// ---- batchnorm stats ----
__global__ void col_stats(const float* __restrict__ X, int M, float* __restrict__ stats) {
    int col = threadIdx.x;  // 128
    float s = 0.f, s2 = 0.f;
    for (int r = blockIdx.x; r < M; r += gridDim.x) {
        float v = X[(size_t)r * 128 + col];
        s += v; s2 += v * v;
    }
    atomicAdd(&stats[col], s);
    atomicAdd(&stats[128 + col], s2);
}

// bn in place; optionally writes bf16 mirror (for downstream GEMM A)
__global__ void bn_apply(float* __restrict__ X, const float* __restrict__ stats,
                         const float* __restrict__ gamma, const float* __restrict__ beta,
                         u16* __restrict__ mirror, int M) {
    int i = blockIdx.x * 256 + threadIdx.x;
    if (i >= M * 128) return;
    int col = i & 127;
    float inv_m = 1.0f / (float)M;
    float mu = stats[col] * inv_m;
    float var = stats[128 + col] * inv_m - mu * mu;
    float g = gamma[col], b = beta[col];
    float v = g * (X[i] - mu) * rsqrtf(var + BN_EPS) + b;
    X[i] = v;
    if (mirror) mirror[i] = f2bf(v);
}

// ---- weff[h*128+k] = sum_c Wd[k, h*128+c] * ad[h*128+c] ----
__global__ void weff_kernel(const float* __restrict__ Wd, const float* __restrict__ ad,
                            float* __restrict__ weff) {
    int t = blockIdx.x * 256 + threadIdx.x;
    if (t >= 512) return;
    int h = t >> 7, k = t & 127;
    float s = 0.f;
    for (int c = 0; c < 128; c++)
        s += Wd[k * 512 + h * 128 + c] * ad[h * 128 + c];
    weff[h * 128 + k] = s;
}

// ---- ld[n,h] = X[n,:] @ weff[h,:]  (one wave per node) ----
__global__ void ld_kernel(const float* __restrict__ X, const float* __restrict__ weff,
                          float* __restrict__ ld, int M) {
    int wid = (blockIdx.x * blockDim.x + threadIdx.x) >> 6;
    int lane = threadIdx.x & 63;
    if (wid >= M) return;
    float x0 = X[(size_t)wid * 128 + lane];
    float x1 = X[(size_t)wid * 128 + 64 + lane];
    #pragma unroll
    for (int h = 0; h < 4; h++) {
        float p = x0 * weff[h * 128 + lane] + x1 * weff[h * 128 + 64 + lane];
        p += __shfl_xor(p, 32, 64);
        p += __shfl_xor(p, 16, 64);
        p += __shfl_xor(p, 8, 64);
        p += __shfl_xor(p, 4, 64);
        p += __shfl_xor(p, 2, 64);
        p += __shfl_xor(p, 1, 64);
        if (lane == 0) ld[wid * 4 + h] = p;
    }
}

// ---- ls[n,h] = sum_c xs[n,h,c]*as[h,c] ----
__global__ void ls_kernel(const u16* __restrict__ xs, const float* __restrict__ as_,
                          float* __restrict__ ls, int M) {
    int wid = (blockIdx.x * blockDim.x + threadIdx.x) >> 6;
    int lane = threadIdx.x & 63;
    if (wid >= M) return;
    float xv[8];
    load_bf16x8(xs + (size_t)wid * 512 + lane * 8, xv);
    const float* ap = as_ + lane * 8;
    float s = 0.f;
    #pragma unroll
    for (int k = 0; k < 8; k++) s += xv[k] * ap[k];
    s += __shfl_xor(s, 1, 64);
    s += __shfl_xor(s, 2, 64);
    s += __shfl_xor(s, 4, 64);
    s += __shfl_xor(s, 8, 64);
    if ((lane & 15) == 0) ls[wid * 4 + (lane >> 4)] = s;
}

// ---------------- CSR build ----------------
__global__ void count_edges(const int* __restrict__ src, const int* __restrict__ dst,
                            int E, int n_loop, int* __restrict__ deg) {
    int e = blockIdx.x * 256 + threadIdx.x;
    if (e >= E + n_loop) return;
    int s, d;
    if (e < E) { s = src[e]; d = dst[e]; if (s == d) return; }
    else { s = e - E; d = s; }
    atomicAdd(&deg[d], 1);
}

__global__ void block_sum(const int* __restrict__ deg, int* __restrict__ bsum, int n) {
    __shared__ int sh[256];
    int i = blockIdx.x * 256 + threadIdx.x;
    sh[threadIdx.x] = (i < n) ? deg[i] : 0;
    __syncthreads();
    for (int s = 128; s > 0; s >>= 1) {
        if (threadIdx.x < s) sh[threadIdx.x] += sh[threadIdx.x + s];
        __syncthreads();
    }
    if (threadIdx.x == 0) bsum[blockIdx.x] = sh[0];
}

__global__ void scan_bsum(int* __restrict__ bsum, int nb, int* __restrict__ total_out) {
    __shared__ int sh[256];
    int tid = threadIdx.x;
    int v = (tid < nb) ? bsum[tid] : 0;
    sh[tid] = v;
    __syncthreads();
    for (int off = 1; off < 256; off <<= 1) {
        int t = (tid >= off) ? sh[tid - off] : 0;
        __syncthreads();
        sh[tid] += t;
        __syncthreads();
    }
    if (tid < nb) bsum[tid] = sh[tid] - v;   // exclusive
    if (tid == 255) *total_out = sh[255];
}

__global__ void scan_final(const int* __restrict__ deg, const int* __restrict__ bsum,
                           int* __restrict__ offs, int* __restrict__ cursor, int n) {
    __shared__ int sh[256];
    int i = blockIdx.x * 256 + threadIdx.x;
    int tid = threadIdx.x;
    int v = (i < n) ? deg[i] : 0;
    sh[tid] = v;
    __syncthreads();
    for (int off = 1; off < 256; off <<= 1) {
        int t = (tid >= off) ? sh[tid - off] : 0;
        __syncthreads();
        sh[tid] += t;
        __syncthreads();
    }
    int ex = bsum[blockIdx.x] + sh[tid] - v;
    if (i < n) { offs[i] = ex; cursor[i] = ex; }
}

__global__ void scatter_edges(const int* __restrict__ src, const int* __restrict__ dst,
                              int E, int n_loop, int* __restrict__ cursor,
                              int* __restrict__ esrc) {
    int e = blockIdx.x * 256 + threadIdx.x;
    if (e >= E + n_loop) return;
    int s, d;
    if (e < E) { s = src[e]; d = dst[e]; if (s == d) return; }
    else { s = e - E; d = s; }
    int pos = atomicAdd(&cursor[d], 1);
    esrc[pos] = s;
}

// ---- GAT aggregation: one wave per dst node; updates xdst_out in place ----
// optionally writes bf16 mirror of the updated rows (A for next rel GEMM)
__global__ void gat_kernel(const int* __restrict__ offs, const int* __restrict__ esrc,
                           const float* __restrict__ ls, const float* __restrict__ ld,
                           const u16* __restrict__ xs, const float* __restrict__ bias,
                           float* __restrict__ xdst_out, u16* __restrict__ mirror, int n_dst) {
    int wid = (blockIdx.x * blockDim.x + threadIdx.x) >> 6;
    int lane = threadIdx.x & 63;
    if (wid >= n_dst) return;
    int h = lane >> 4;
    int beg = offs[wid], end = offs[wid + 1];
    float ldv = ld[wid * 4 + h];
    float m = -INFINITY;
    for (int j = beg; j < end; j++) {
        int s = esrc[j];
        float l = ls[s * 4 + h] + ldv;
        l = l > 0.f ? l : 0.2f * l;
        m = fmaxf(m, l);
    }
    float denom = 0.f;
    float acc[8] = {0.f, 0.f, 0.f, 0.f, 0.f, 0.f, 0.f, 0.f};
    for (int j = beg; j < end; j++) {
        int s = esrc[j];
        float l = ls[s * 4 + h] + ldv;
        l = l > 0.f ? l : 0.2f * l;
        float p = __expf(l - m);
        denom += p;
        float xv[8];
        load_bf16x8(xs + (size_t)s * 512 + lane * 8, xv);
        #pragma unroll
        for (int k = 0; k < 8; k++) acc[k] += p * xv[k];
    }
    float dinv = denom > 0.f ? 1.f / denom : 1.f;
    #pragma unroll
    for (int k = 0; k < 8; k++) {
        float v = acc[k] * dinv;
        v += __shfl_xor(v, 16, 64);
        v += __shfl_xor(v, 32, 64);
        acc[k] = v * 0.25f;
    }
    if (lane < 16) {
        int c0 = lane * 8;
        #pragma unroll
        for (int k = 0; k < 8; k++) {
            float v = xdst_out[(size_t)wid * 128 + c0 + k] + acc[k] + bias[c0 + k];
            xdst_out[(size_t)wid * 128 + c0 + k] = v;
            if (mirror) mirror[(size_t)wid * 128 + c0 + k] = f2bf(v);
        }
    }
}

static inline int cdiv(int a, int b) { return (a + b - 1) / b; }

extern "C" void kernel_launch(void* const* d_in, const int* in_sizes, int n_in,
                              void* d_out, int out_size, void* d_ws, size_t ws_size,
                              hipStream_t stream) {
    const float* x_gene = (const float*)d_in[0];
    const float* x_dis  = (const float*)d_in[1];
    const int* e1s = (const int*)d_in[2];
    const int* e1d = (const int*)d_in[3];
    const int* e2s = (const int*)d_in[4];
    const int* e2d = (const int*)d_in[5];
    const float *Wg = (const float*)d_in[6],  *bg = (const float*)d_in[7];
    const float *gg = (const float*)d_in[8],  *betag = (const float*)d_in[9];
    const float *Wd = (const float*)d_in[10], *bd = (const float*)d_in[11];
    const float *gd = (const float*)d_in[12], *betad = (const float*)d_in[13];
    const float *W1s = (const float*)d_in[14], *W1d = (const float*)d_in[15];
    const float *a1s = (const float*)d_in[16], *a1d = (const float*)d_in[17];
    const float *b1  = (const float*)d_in[18];
    const float *W2s = (const float*)d_in[19], *W2d = (const float*)d_in[20];
    const float *a2s = (const float*)d_in[21], *a2d = (const float*)d_in[22];
    const float *b2  = (const float*)d_in[23];

    float* gene_f = (float*)d_out;                         // [N_GENE,128]
    float* dis_f  = (float*)d_out + (size_t)N_GENE * 128;  // [N_DIS,128]

    char* p = (char*)d_ws;
    auto alloc = [&](size_t bytes) {
        char* r = p;
        p += (bytes + 255) & ~(size_t)255;
        return r;
    };
    u16*   xs_buf  = (u16*)  alloc((size_t)N_GENE * 512 * 2);
    u16*   gene_bf = (u16*)  alloc((size_t)N_GENE * 128 * 2);
    u16*   dis_bf  = (u16*)  alloc((size_t)N_DIS * 128 * 2);
    float* ls_buf  = (float*)alloc((size_t)N_GENE * 4 * 4);
    float* ld_buf  = (float*)alloc((size_t)N_GENE * 4 * 4);
    float* weff    = (float*)alloc(512 * 4);
    float* stats   = (float*)alloc(256 * 4);
    int*   deg     = (int*)  alloc((size_t)N_GENE * 4);
    int*   offs    = (int*)  alloc((size_t)(N_GENE + 1) * 4);
    int*   cursor  = (int*)  alloc((size_t)N_GENE * 4);
    int*   bsum    = (int*)  alloc(256 * 4);
    int*   esrc    = (int*)  alloc((size_t)(E_EDGES + N_GENE) * 4);
    u16*   Wgt  = (u16*)alloc((size_t)512 * 128 * 2);
    u16*   Wdt  = (u16*)alloc((size_t)256 * 128 * 2);
    u16*   W1st = (u16*)alloc((size_t)128 * 512 * 2);
    u16*   W2st = (u16*)alloc((size_t)128 * 512 * 2);

    const int NB = cdiv(N_GENE, 256);  // 196

    // ---- weight pre-transpose to bf16 [n][k] ----
    wtrans_kernel<<<256, 256, 0, stream>>>(Wg,  Wgt,  512, 128);
    wtrans_kernel<<<128, 256, 0, stream>>>(Wd,  Wdt,  256, 128);
    wtrans_kernel<<<256, 256, 0, stream>>>(W1s, W1st, 128, 512);
    wtrans_kernel<<<256, 256, 0, stream>>>(W2s, W2st, 128, 512);

    // ---- encode gene ----
    zero_kernel<<<1, 256, 0, stream>>>((int*)stats, 256);
    mfma_gemm<512, 128, false, true, false><<<dim3(cdiv(N_GENE, 64), 1), 256, 0, stream>>>(x_gene, Wgt, bg, gene_f, N_GENE);
    col_stats<<<512, 128, 0, stream>>>(gene_f, N_GENE, stats);
    bn_apply<<<cdiv(N_GENE * 128, 256), 256, 0, stream>>>(gene_f, stats, gg, betag, nullptr, N_GENE);

    // ---- encode dis ----
    zero_kernel<<<1, 256, 0, stream>>>((int*)stats, 256);
    mfma_gemm<256, 128, false, true, false><<<dim3(cdiv(N_DIS, 64), 1), 256, 0, stream>>>(x_dis, Wdt, bd, dis_f, N_DIS);
    col_stats<<<512, 128, 0, stream>>>(dis_f, N_DIS, stats);
    bn_apply<<<cdiv(N_DIS * 128, 256), 256, 0, stream>>>(dis_f, stats, gd, betad, dis_bf, N_DIS);

    // ---- relation 1: Disease -> Gene ----
    mfma_gemm<128, 512, true, false, true><<<dim3(cdiv(N_DIS, 64), 4), 256, 0, stream>>>(dis_bf, W1st, nullptr, xs_buf, N_DIS);
    ls_kernel<<<cdiv(N_DIS, 4), 256, 0, stream>>>(xs_buf, a1s, ls_buf, N_DIS);
    weff_kernel<<<2, 256, 0, stream>>>(W1d, a1d, weff);
    ld_kernel<<<cdiv(N_GENE, 4), 256, 0, stream>>>(gene_f, weff, ld_buf, N_GENE);
    zero_kernel<<<cdiv(N_GENE, 256), 256, 0, stream>>>(deg, N_GENE);
    count_edges<<<cdiv(E_EDGES + N_DIS, 256), 256, 0, stream>>>(e1s, e1d, E_EDGES, N_DIS, deg);
    block_sum<<<NB, 256, 0, stream>>>(deg, bsum, N_GENE);
    scan_bsum<<<1, 256, 0, stream>>>(bsum, NB, &offs[N_GENE]);
    scan_final<<<NB, 256, 0, stream>>>(deg, bsum, offs, cursor, N_GENE);
    scatter_edges<<<cdiv(E_EDGES + N_DIS, 256), 256, 0, stream>>>(e1s, e1d, E_EDGES, N_DIS, cursor, esrc);
    gat_kernel<<<cdiv(N_GENE, 4), 256, 0, stream>>>(offs, esrc, ls_buf, ld_buf, xs_buf, b1, gene_f, gene_bf, N_GENE);

    // ---- relation 2: Gene -> Gene ----
    mfma_gemm<128, 512, true, false, true><<<dim3(cdiv(N_GENE, 64), 4), 256, 0, stream>>>(gene_bf, W2st, nullptr, xs_buf, N_GENE);
    ls_kernel<<<cdiv(N_GENE, 4), 256, 0, stream>>>(xs_buf, a2s, ls_buf, N_GENE);
    weff_kernel<<<2, 256, 0, stream>>>(W2d, a2d, weff);
    ld_kernel<<<cdiv(N_GENE, 4), 256, 0, stream>>>(gene_f, weff, ld_buf, N_GENE);
    zero_kernel<<<cdiv(N_GENE, 256), 256, 0, stream>>>(deg, N_GENE);
    count_edges<<<cdiv(E_EDGES + N_GENE, 256), 256, 0, stream>>>(e2s, e2d, E_EDGES, N_GENE, deg);
    block_sum<<<NB, 256, 0, stream>>>(deg, bsum, N_GENE);
    scan_bsum<<<1, 256, 0, stream>>>(bsum, NB, &offs[N_GENE]);
    scan_final<<<NB, 256, 0, stream>>>(deg, bsum, offs, cursor, N_GENE);
    scatter_edges<<<cdiv(E_EDGES + N_GENE, 256), 256, 0, stream>>>(e2s, e2d, E_EDGES, N_GENE, cursor, esrc);
    gat_kernel<<<cdiv(N_GENE, 4), 256, 0, stream>>>(offs, esrc, ls_buf, ld_buf, xs_buf, b2, gene_f, nullptr, N_GENE);
}

// Round 6
// 612.002 us; speedup vs baseline: 1.1944x; 1.1944x over previous
//
#include <hip/hip_runtime.h>
#include <hip/hip_bf16.h>
#include <math.h>

#define N_GENE 50000
#define N_DIS  25000
#define F_GENE 512
#define F_DIS  256
#define E_EDGES 150000
#define BN_EPS 1e-5f

typedef unsigned short u16;
typedef short s16x8 __attribute__((ext_vector_type(8)));
typedef float f32x4 __attribute__((ext_vector_type(4)));

__device__ __forceinline__ u16 f2bf(float f) {
    union { float f; unsigned u; } c; c.f = f;
    unsigned u = c.u;
    unsigned rounding = 0x7FFFu + ((u >> 16) & 1u);
    return (u16)((u + rounding) >> 16);
}
__device__ __forceinline__ void load_bf16x8(const u16* p, float* f) {
    uint4 q = *reinterpret_cast<const uint4*>(p);
    unsigned w0 = q.x, w1 = q.y, w2 = q.z, w3 = q.w;
    f[0] = __uint_as_float(w0 << 16); f[1] = __uint_as_float(w0 & 0xffff0000u);
    f[2] = __uint_as_float(w1 << 16); f[3] = __uint_as_float(w1 & 0xffff0000u);
    f[4] = __uint_as_float(w2 << 16); f[5] = __uint_as_float(w2 & 0xffff0000u);
    f[6] = __uint_as_float(w3 << 16); f[7] = __uint_as_float(w3 & 0xffff0000u);
}

// ---------------- zero fill ----------------
__global__ void zero_kernel(int* p, int n) {
    int i = blockIdx.x * 256 + threadIdx.x;
    if (i < n) p[i] = 0;
}

// ---- B pack: W f32 [K][N] -> fragment-major bf16 Bp[nt][KC][64][8]
// frag coords: nt=n>>4, mr=n&15, kc=k>>5, quad=(k>>3)&3, j=k&7, lane=quad*16+mr
__global__ void pack_b(const float* __restrict__ W, u16* __restrict__ Bp, int K, int N) {
    int i = blockIdx.x * 256 + threadIdx.x;
    int K8 = K >> 3;
    if (i >= N * K8) return;
    int n = i / K8, ko = i - n * K8;
    int k0 = ko * 8;
    int nt = n >> 4, mr = n & 15, kc = k0 >> 5, quad = (k0 >> 3) & 3;
    u16 tmp[8];
#pragma unroll
    for (int j = 0; j < 8; j++) tmp[j] = f2bf(W[(size_t)(k0 + j) * N + n]);
    *reinterpret_cast<uint4*>(&Bp[((size_t)(nt * (K >> 5) + kc) * 64 + quad * 16 + mr) * 8]) =
        *reinterpret_cast<const uint4*>(tmp);
}

// ---- GEMM with LDS-staged fragment-major B ----
// out[M,NFULL] 128-col slab = A[M,K] @ B^T. A: f32 row-major or bf16 fragment-major.
// Block: 4 waves x 16 rows. B staged in 32KB chunks (8 ntiles x CK kc-frags).
template <int K, bool A_FRAG, bool RELU_BIAS, bool OUT_BF16>
__global__ __launch_bounds__(256) void gemm_lds(const void* __restrict__ Ap,
                                                const u16* __restrict__ Bp,
                                                const float* __restrict__ bias,
                                                void* __restrict__ outp, int M, int NFULL) {
    constexpr int KC = K / 32;
    constexpr int CK = (KC < 4) ? KC : 4;    // kc per staged chunk
    constexpr int NCH = KC / CK;
    __shared__ u16 Bs[8 * CK * 64 * 8];      // 32 KB at CK=4
    const int wave = threadIdx.x >> 6;
    const int lane = threadIdx.x & 63;
    const int mrow = lane & 15;
    const int quad = lane >> 4;
    const int m0 = (blockIdx.x * 4 + wave) * 16;
    const int n0 = blockIdx.y * 128;
    const int arow = (m0 + mrow < M) ? m0 + mrow : M - 1;
    const int rt = (m0 >> 4) < ((M + 15) >> 4) ? (m0 >> 4) : ((M + 15) >> 4) - 1;
    const u16* bslab = Bp + (size_t)(n0 >> 4) * KC * 512;  // 512 u16 per frag

    f32x4 acc[8];
#pragma unroll
    for (int t = 0; t < 8; t++) acc[t] = (f32x4){0.f, 0.f, 0.f, 0.f};

    for (int c = 0; c < NCH; c++) {
        // stage 8*CK frags (1KB each), 2*CK per wave, coalesced 16B/lane
#pragma unroll
        for (int q = 0; q < 2 * CK; q++) {
            int fi = wave * 2 * CK + q;
            int t = fi / CK, kcp = fi % CK;
            const u16* g = bslab + ((size_t)(t * KC + c * CK + kcp) * 64 + lane) * 8;
            *reinterpret_cast<uint4*>(&Bs[(size_t)fi * 512 + (size_t)lane * 8]) =
                *reinterpret_cast<const uint4*>(g);
        }
        __syncthreads();
#pragma unroll
        for (int kcp = 0; kcp < CK; kcp++) {
            int kc = c * CK + kcp;
            s16x8 af;
            if (A_FRAG) {
                af = *reinterpret_cast<const s16x8*>(
                    (const u16*)Ap + ((size_t)(rt * KC + kc) * 64 + lane) * 8);
            } else {
                const float* ap = (const float*)Ap + (size_t)arow * K + kc * 32 + quad * 8;
                float4 lo = *reinterpret_cast<const float4*>(ap);
                float4 hi = *reinterpret_cast<const float4*>(ap + 4);
                af[0] = (short)f2bf(lo.x); af[1] = (short)f2bf(lo.y);
                af[2] = (short)f2bf(lo.z); af[3] = (short)f2bf(lo.w);
                af[4] = (short)f2bf(hi.x); af[5] = (short)f2bf(hi.y);
                af[6] = (short)f2bf(hi.z); af[7] = (short)f2bf(hi.w);
            }
#pragma unroll
            for (int t = 0; t < 8; t++) {
                const s16x8 bfr = *reinterpret_cast<const s16x8*>(
                    &Bs[((size_t)(t * CK + kcp) * 64 + lane) * 8]);
                acc[t] = __builtin_amdgcn_mfma_f32_16x16x32_bf16(af, bfr, acc[t], 0, 0, 0);
            }
        }
        if (c + 1 < NCH) __syncthreads();
    }

#pragma unroll
    for (int t = 0; t < 8; t++) {
        int col = n0 + t * 16 + mrow;
#pragma unroll
        for (int r = 0; r < 4; r++) {
            int orow = m0 + quad * 4 + r;
            if (orow < M) {
                float v = acc[t][r];
                if (RELU_BIAS) v = fmaxf(v + bias[col], 0.f);
                if (OUT_BF16)
                    ((u16*)outp)[(size_t)orow * NFULL + col] = f2bf(v);
                else
                    ((float*)outp)[(size_t)orow * NFULL + col] = v;
            }
        }
    }
}

// ---- batchnorm stats ----
__global__ void col_stats(const float* __restrict__ X, int M, float* __restrict__ stats) {
    int col = threadIdx.x;  // 128
    float s = 0.f, s2 = 0.f;
    for (int r = blockIdx.x; r < M; r += gridDim.x) {
        float v = X[(size_t)r * 128 + col];
        s += v; s2 += v * v;
    }
    atomicAdd(&stats[col], s);
    atomicAdd(&stats[128 + col], s2);
}

// bn in place; optional bf16 FRAGMENT-MAJOR mirror (A for rel GEMM, K=128 -> KC=4)
__global__ void bn_apply(float* __restrict__ X, const float* __restrict__ stats,
                         const float* __restrict__ gamma, const float* __restrict__ beta,
                         u16* __restrict__ mirror, int M) {
    int i = blockIdx.x * 256 + threadIdx.x;   // M*16 threads, 8 cols each
    if (i >= M * 16) return;
    int row = i >> 4, cg = i & 15;
    float inv_m = 1.0f / (float)M;
    float4 lo = *reinterpret_cast<const float4*>(&X[(size_t)row * 128 + cg * 8]);
    float4 hi = *reinterpret_cast<const float4*>(&X[(size_t)row * 128 + cg * 8 + 4]);
    float v[8] = {lo.x, lo.y, lo.z, lo.w, hi.x, hi.y, hi.z, hi.w};
    u16 mb[8];
#pragma unroll
    for (int e = 0; e < 8; e++) {
        int col = cg * 8 + e;
        float mu = stats[col] * inv_m;
        float var = stats[128 + col] * inv_m - mu * mu;
        v[e] = gamma[col] * (v[e] - mu) * rsqrtf(var + BN_EPS) + beta[col];
        mb[e] = f2bf(v[e]);
    }
    *reinterpret_cast<float4*>(&X[(size_t)row * 128 + cg * 8]) = (float4){v[0], v[1], v[2], v[3]};
    *reinterpret_cast<float4*>(&X[(size_t)row * 128 + cg * 8 + 4]) = (float4){v[4], v[5], v[6], v[7]};
    if (mirror) {
        int kc = cg >> 2, quad = cg & 3, ml = quad * 16 + (row & 15), rt = row >> 4;
        *reinterpret_cast<uint4*>(&mirror[((size_t)(rt * 4 + kc) * 64 + ml) * 8]) =
            *reinterpret_cast<const uint4*>(mb);
    }
}

// ---- weff[h*128+k] = sum_c Wd[k, h*128+c] * ad[h*128+c] ----
__global__ void weff_kernel(const float* __restrict__ Wd, const float* __restrict__ ad,
                            float* __restrict__ weff) {
    int t = blockIdx.x * 256 + threadIdx.x;
    if (t >= 512) return;
    int h = t >> 7, k = t & 127;
    float s = 0.f;
    for (int c = 0; c < 128; c++)
        s += Wd[k * 512 + h * 128 + c] * ad[h * 128 + c];
    weff[h * 128 + k] = s;
}

// ---- ld[n,h] = X[n,:] @ weff[h,:]  (one wave per node) ----
__global__ void ld_kernel(const float* __restrict__ X, const float* __restrict__ weff,
                          float* __restrict__ ld, int M) {
    int wid = (blockIdx.x * blockDim.x + threadIdx.x) >> 6;
    int lane = threadIdx.x & 63;
    if (wid >= M) return;
    float x0 = X[(size_t)wid * 128 + lane];
    float x1 = X[(size_t)wid * 128 + 64 + lane];
    #pragma unroll
    for (int h = 0; h < 4; h++) {
        float p = x0 * weff[h * 128 + lane] + x1 * weff[h * 128 + 64 + lane];
        p += __shfl_xor(p, 32, 64);
        p += __shfl_xor(p, 16, 64);
        p += __shfl_xor(p, 8, 64);
        p += __shfl_xor(p, 4, 64);
        p += __shfl_xor(p, 2, 64);
        p += __shfl_xor(p, 1, 64);
        if (lane == 0) ld[wid * 4 + h] = p;
    }
}

// ---- ls[n,h] = sum_c xs[n,h,c]*as[h,c] ----
__global__ void ls_kernel(const u16* __restrict__ xs, const float* __restrict__ as_,
                          float* __restrict__ ls, int M) {
    int wid = (blockIdx.x * blockDim.x + threadIdx.x) >> 6;
    int lane = threadIdx.x & 63;
    if (wid >= M) return;
    float xv[8];
    load_bf16x8(xs + (size_t)wid * 512 + lane * 8, xv);
    const float* ap = as_ + lane * 8;
    float s = 0.f;
    #pragma unroll
    for (int k = 0; k < 8; k++) s += xv[k] * ap[k];
    s += __shfl_xor(s, 1, 64);
    s += __shfl_xor(s, 2, 64);
    s += __shfl_xor(s, 4, 64);
    s += __shfl_xor(s, 8, 64);
    if ((lane & 15) == 0) ls[wid * 4 + (lane >> 4)] = s;
}

// ---------------- CSR build ----------------
__global__ void count_edges(const int* __restrict__ src, const int* __restrict__ dst,
                            int E, int n_loop, int* __restrict__ deg) {
    int e = blockIdx.x * 256 + threadIdx.x;
    if (e >= E + n_loop) return;
    int s, d;
    if (e < E) { s = src[e]; d = dst[e]; if (s == d) return; }
    else { s = e - E; d = s; }
    atomicAdd(&deg[d], 1);
}

__global__ void block_sum(const int* __restrict__ deg, int* __restrict__ bsum, int n) {
    __shared__ int sh[256];
    int i = blockIdx.x * 256 + threadIdx.x;
    sh[threadIdx.x] = (i < n) ? deg[i] : 0;
    __syncthreads();
    for (int s = 128; s > 0; s >>= 1) {
        if (threadIdx.x < s) sh[threadIdx.x] += sh[threadIdx.x + s];
        __syncthreads();
    }
    if (threadIdx.x == 0) bsum[blockIdx.x] = sh[0];
}

__global__ void scan_bsum(int* __restrict__ bsum, int nb, int* __restrict__ total_out) {
    __shared__ int sh[256];
    int tid = threadIdx.x;
    int v = (tid < nb) ? bsum[tid] : 0;
    sh[tid] = v;
    __syncthreads();
    for (int off = 1; off < 256; off <<= 1) {
        int t = (tid >= off) ? sh[tid - off] : 0;
        __syncthreads();
        sh[tid] += t;
        __syncthreads();
    }
    if (tid < nb) bsum[tid] = sh[tid] - v;   // exclusive
    if (tid == 255) *total_out = sh[255];
}

__global__ void scan_final(const int* __restrict__ deg, const int* __restrict__ bsum,
                           int* __restrict__ offs, int* __restrict__ cursor, int n) {
    __shared__ int sh[256];
    int i = blockIdx.x * 256 + threadIdx.x;
    int tid = threadIdx.x;
    int v = (i < n) ? deg[i] : 0;
    sh[tid] = v;
    __syncthreads();
    for (int off = 1; off < 256; off <<= 1) {
        int t = (tid >= off) ? sh[tid - off] : 0;
        __syncthreads();
        sh[tid] += t;
        __syncthreads();
    }
    int ex = bsum[blockIdx.x] + sh[tid] - v;
    if (i < n) { offs[i] = ex; cursor[i] = ex; }
}

__global__ void scatter_edges(const int* __restrict__ src, const int* __restrict__ dst,
                              int E, int n_loop, int* __restrict__ cursor,
                              int* __restrict__ esrc) {
    int e = blockIdx.x * 256 + threadIdx.x;
    if (e >= E + n_loop) return;
    int s, d;
    if (e < E) { s = src[e]; d = dst[e]; if (s == d) return; }
    else { s = e - E; d = s; }
    int pos = atomicAdd(&cursor[d], 1);
    esrc[pos] = s;
}

// ---- GAT aggregation: one wave per dst node; updates xdst_out in place ----
// optional bf16 FRAGMENT-MAJOR mirror (A for next rel GEMM, KC=4)
__global__ void gat_kernel(const int* __restrict__ offs, const int* __restrict__ esrc,
                           const float* __restrict__ ls, const float* __restrict__ ld,
                           const u16* __restrict__ xs, const float* __restrict__ bias,
                           float* __restrict__ xdst_out, u16* __restrict__ mirror, int n_dst) {
    int wid = (blockIdx.x * blockDim.x + threadIdx.x) >> 6;
    int lane = threadIdx.x & 63;
    if (wid >= n_dst) return;
    int h = lane >> 4;
    int beg = offs[wid], end = offs[wid + 1];
    float ldv = ld[wid * 4 + h];
    float m = -INFINITY;
    for (int j = beg; j < end; j++) {
        int s = esrc[j];
        float l = ls[s * 4 + h] + ldv;
        l = l > 0.f ? l : 0.2f * l;
        m = fmaxf(m, l);
    }
    float denom = 0.f;
    float acc[8] = {0.f, 0.f, 0.f, 0.f, 0.f, 0.f, 0.f, 0.f};
    for (int j = beg; j < end; j++) {
        int s = esrc[j];
        float l = ls[s * 4 + h] + ldv;
        l = l > 0.f ? l : 0.2f * l;
        float p = __expf(l - m);
        denom += p;
        float xv[8];
        load_bf16x8(xs + (size_t)s * 512 + lane * 8, xv);
        #pragma unroll
        for (int k = 0; k < 8; k++) acc[k] += p * xv[k];
    }
    float dinv = denom > 0.f ? 1.f / denom : 1.f;
    #pragma unroll
    for (int k = 0; k < 8; k++) {
        float v = acc[k] * dinv;
        v += __shfl_xor(v, 16, 64);
        v += __shfl_xor(v, 32, 64);
        acc[k] = v * 0.25f;
    }
    if (lane < 16) {
        int c0 = lane * 8;
        float vout[8];
        #pragma unroll
        for (int k = 0; k < 8; k++) {
            vout[k] = xdst_out[(size_t)wid * 128 + c0 + k] + acc[k] + bias[c0 + k];
            xdst_out[(size_t)wid * 128 + c0 + k] = vout[k];
        }
        if (mirror) {
            unsigned pk[4];
            #pragma unroll
            for (int kk = 0; kk < 4; kk++)
                pk[kk] = (unsigned)f2bf(vout[2 * kk]) | ((unsigned)f2bf(vout[2 * kk + 1]) << 16);
            int kc = lane >> 2, quad = lane & 3, ml = quad * 16 + (wid & 15), rt = wid >> 4;
            *reinterpret_cast<uint4*>(&mirror[((size_t)(rt * 4 + kc) * 64 + ml) * 8]) =
                *reinterpret_cast<const uint4*>(pk);
        }
    }
}

static inline int cdiv(int a, int b) { return (a + b - 1) / b; }

extern "C" void kernel_launch(void* const* d_in, const int* in_sizes, int n_in,
                              void* d_out, int out_size, void* d_ws, size_t ws_size,
                              hipStream_t stream) {
    const float* x_gene = (const float*)d_in[0];
    const float* x_dis  = (const float*)d_in[1];
    const int* e1s = (const int*)d_in[2];
    const int* e1d = (const int*)d_in[3];
    const int* e2s = (const int*)d_in[4];
    const int* e2d = (const int*)d_in[5];
    const float *Wg = (const float*)d_in[6],  *bg = (const float*)d_in[7];
    const float *gg = (const float*)d_in[8],  *betag = (const float*)d_in[9];
    const float *Wd = (const float*)d_in[10], *bd = (const float*)d_in[11];
    const float *gd = (const float*)d_in[12], *betad = (const float*)d_in[13];
    const float *W1s = (const float*)d_in[14], *W1d = (const float*)d_in[15];
    const float *a1s = (const float*)d_in[16], *a1d = (const float*)d_in[17];
    const float *b1  = (const float*)d_in[18];
    const float *W2s = (const float*)d_in[19], *W2d = (const float*)d_in[20];
    const float *a2s = (const float*)d_in[21], *a2d = (const float*)d_in[22];
    const float *b2  = (const float*)d_in[23];

    float* gene_f = (float*)d_out;                         // [N_GENE,128]
    float* dis_f  = (float*)d_out + (size_t)N_GENE * 128;  // [N_DIS,128]

    char* p = (char*)d_ws;
    auto alloc = [&](size_t bytes) {
        char* r = p;
        p += (bytes + 255) & ~(size_t)255;
        return r;
    };
    u16*   xs_buf  = (u16*)  alloc((size_t)N_GENE * 512 * 2);
    // fragment-major bf16 mirrors: cdiv(M,16) tiles x 4 kc x 64 lanes x 8
    u16*   gene_bf = (u16*)  alloc((size_t)cdiv(N_GENE, 16) * 2048 * 2);
    u16*   dis_bf  = (u16*)  alloc((size_t)cdiv(N_DIS, 16) * 2048 * 2);
    float* ls_buf  = (float*)alloc((size_t)N_GENE * 4 * 4);
    float* ld_buf  = (float*)alloc((size_t)N_GENE * 4 * 4);
    float* weff    = (float*)alloc(512 * 4);
    float* stats   = (float*)alloc(256 * 4);
    int*   deg     = (int*)  alloc((size_t)N_GENE * 4);
    int*   offs    = (int*)  alloc((size_t)(N_GENE + 1) * 4);
    int*   cursor  = (int*)  alloc((size_t)N_GENE * 4);
    int*   bsum    = (int*)  alloc(256 * 4);
    int*   esrc    = (int*)  alloc((size_t)(E_EDGES + N_GENE) * 4);
    u16*   Wgt  = (u16*)alloc((size_t)8 * 16 * 512 * 2);   // [8nt][16kc][512]
    u16*   Wdt  = (u16*)alloc((size_t)8 * 8 * 512 * 2);    // [8nt][8kc][512]
    u16*   W1st = (u16*)alloc((size_t)32 * 4 * 512 * 2);   // [32nt][4kc][512]
    u16*   W2st = (u16*)alloc((size_t)32 * 4 * 512 * 2);

    const int NB = cdiv(N_GENE, 256);  // 196

    // ---- weight pack to fragment-major bf16 ----
    pack_b<<<cdiv(128 * 64, 256), 256, 0, stream>>>(Wg,  Wgt,  512, 128);
    pack_b<<<cdiv(128 * 32, 256), 256, 0, stream>>>(Wd,  Wdt,  256, 128);
    pack_b<<<cdiv(512 * 16, 256), 256, 0, stream>>>(W1s, W1st, 128, 512);
    pack_b<<<cdiv(512 * 16, 256), 256, 0, stream>>>(W2s, W2st, 128, 512);

    // ---- encode gene ----
    zero_kernel<<<1, 256, 0, stream>>>((int*)stats, 256);
    gemm_lds<512, false, true, false><<<dim3(cdiv(N_GENE, 64), 1), 256, 0, stream>>>(
        x_gene, Wgt, bg, gene_f, N_GENE, 128);
    col_stats<<<512, 128, 0, stream>>>(gene_f, N_GENE, stats);
    bn_apply<<<cdiv(N_GENE * 16, 256), 256, 0, stream>>>(gene_f, stats, gg, betag, nullptr, N_GENE);

    // ---- encode dis ----
    zero_kernel<<<1, 256, 0, stream>>>((int*)stats, 256);
    gemm_lds<256, false, true, false><<<dim3(cdiv(N_DIS, 64), 1), 256, 0, stream>>>(
        x_dis, Wdt, bd, dis_f, N_DIS, 128);
    col_stats<<<512, 128, 0, stream>>>(dis_f, N_DIS, stats);
    bn_apply<<<cdiv(N_DIS * 16, 256), 256, 0, stream>>>(dis_f, stats, gd, betad, dis_bf, N_DIS);

    // ---- relation 1: Disease -> Gene ----
    gemm_lds<128, true, false, true><<<dim3(cdiv(N_DIS, 64), 4), 256, 0, stream>>>(
        dis_bf, W1st, nullptr, xs_buf, N_DIS, 512);
    ls_kernel<<<cdiv(N_DIS, 4), 256, 0, stream>>>(xs_buf, a1s, ls_buf, N_DIS);
    weff_kernel<<<2, 256, 0, stream>>>(W1d, a1d, weff);
    ld_kernel<<<cdiv(N_GENE, 4), 256, 0, stream>>>(gene_f, weff, ld_buf, N_GENE);
    zero_kernel<<<cdiv(N_GENE, 256), 256, 0, stream>>>(deg, N_GENE);
    count_edges<<<cdiv(E_EDGES + N_DIS, 256), 256, 0, stream>>>(e1s, e1d, E_EDGES, N_DIS, deg);
    block_sum<<<NB, 256, 0, stream>>>(deg, bsum, N_GENE);
    scan_bsum<<<1, 256, 0, stream>>>(bsum, NB, &offs[N_GENE]);
    scan_final<<<NB, 256, 0, stream>>>(deg, bsum, offs, cursor, N_GENE);
    scatter_edges<<<cdiv(E_EDGES + N_DIS, 256), 256, 0, stream>>>(e1s, e1d, E_EDGES, N_DIS, cursor, esrc);
    gat_kernel<<<cdiv(N_GENE, 4), 256, 0, stream>>>(offs, esrc, ls_buf, ld_buf, xs_buf, b1, gene_f, gene_bf, N_GENE);

    // ---- relation 2: Gene -> Gene ----
    gemm_lds<128, true, false, true><<<dim3(cdiv(N_GENE, 64), 4), 256, 0, stream>>>(
        gene_bf, W2st, nullptr, xs_buf, N_GENE, 512);
    ls_kernel<<<cdiv(N_GENE, 4), 256, 0, stream>>>(xs_buf, a2s, ls_buf, N_GENE);
    weff_kernel<<<2, 256, 0, stream>>>(W2d, a2d, weff);
    ld_kernel<<<cdiv(N_GENE, 4), 256, 0, stream>>>(gene_f, weff, ld_buf, N_GENE);
    zero_kernel<<<cdiv(N_GENE, 256), 256, 0, stream>>>(deg, N_GENE);
    count_edges<<<cdiv(E_EDGES + N_GENE, 256), 256, 0, stream>>>(e2s, e2d, E_EDGES, N_GENE, deg);
    block_sum<<<NB, 256, 0, stream>>>(deg, bsum, N_GENE);
    scan_bsum<<<1, 256, 0, stream>>>(bsum, NB, &offs[N_GENE]);
    scan_final<<<NB, 256, 0, stream>>>(deg, bsum, offs, cursor, N_GENE);
    scatter_edges<<<cdiv(E_EDGES + N_GENE, 256), 256, 0, stream>>>(e2s, e2d, E_EDGES, N_GENE, cursor, esrc);
    gat_kernel<<<cdiv(N_GENE, 4), 256, 0, stream>>>(offs, esrc, ls_buf, ld_buf, xs_buf, b2, gene_f, nullptr, N_GENE);
}